// Round 3
// baseline (138.358 us; speedup 1.0000x reference)
//
#include <hip/hip_runtime.h>

// GraphSAGE fused forward — live path only (neighbors_2/W1 are dead code).
//
//   d_in[0] nodes        int32 [4096]
//   d_in[1] neighbors_1  int32 [4096,16]
//   d_in[2] neighbors_2  (UNUSED)
//   d_in[3] node_features f32  [100000,128]
//   d_in[4] W1           (UNUSED)
//   d_in[5] W2           f32   [128,256]
//   d_in[6] Wo           f32   [64,128]
// out: softmax(relu(cat[feat, mean_nbr] @ W2^T) @ Wo^T)  f32 [4096,64]

constexpr int D = 128;
constexpr int H = 128;
constexpr int O = 64;
constexpr int S = 16;
constexpr int NB = 4096;
constexpr int SPB = 4;       // seeds per block -> 1024 blocks = 4 blocks/CU
constexpr int THREADS = 256; // 4 waves/block, one wave per seed in gather/output

__global__ __launch_bounds__(THREADS, 4) void sage_fused(
    const int* __restrict__ nodes,
    const int* __restrict__ neighbors_1,
    const float* __restrict__ node_features,
    const float* __restrict__ W2,
    const float* __restrict__ Wo,
    float* __restrict__ out)
{
    __shared__ float cat[SPB][2 * D];      // [origin | mean]   4 KB
    __shared__ float part[THREADS][9];     // stride-9: conflict-free  9 KB
    __shared__ float h[SPB][H];            // 2 KB

    const int t = threadIdx.x;
    const int seed0 = blockIdx.x * SPB;

    // ---- gather: one wave per seed. lanes 0-31 = neighbors 0-7 (+origin),
    //      lanes 32-63 = neighbors 8-15. float4 per lane, combine via shfl_xor(32).
    {
        const int lane = t & 63;
        const int r    = __builtin_amdgcn_readfirstlane(t >> 6); // wave-uniform seed
        const int d4   = lane & 31;        // float4 column 0..31
        const int sub  = lane >> 5;        // which 8-neighbor half
        const float4* nf = reinterpret_cast<const float4*>(node_features);

        // 8 contiguous neighbor ids for this half (two int4 loads, L1/L2-hit)
        const int4* nbp = reinterpret_cast<const int4*>(
            neighbors_1 + (size_t)(seed0 + r) * S + sub * 8);
        const int4 n0 = nbp[0];
        const int4 n1 = nbp[1];

        float4 sum = make_float4(0.f, 0.f, 0.f, 0.f);
        const int ids[8] = {n0.x, n0.y, n0.z, n0.w, n1.x, n1.y, n1.z, n1.w};
        #pragma unroll
        for (int s = 0; s < 8; ++s) {
            const float4 v = nf[(size_t)ids[s] * (D / 4) + d4];
            sum.x += v.x; sum.y += v.y; sum.z += v.z; sum.w += v.w;
        }
        // combine the two halves (all 64 lanes execute the shuffles)
        float4 tot;
        tot.x = sum.x + __shfl_xor(sum.x, 32);
        tot.y = sum.y + __shfl_xor(sum.y, 32);
        tot.z = sum.z + __shfl_xor(sum.z, 32);
        tot.w = sum.w + __shfl_xor(sum.w, 32);

        if (sub == 0) {
            const int org = nodes[seed0 + r];
            const float4 ov = nf[(size_t)org * (D / 4) + d4];
            *reinterpret_cast<float4*>(&cat[r][4 * d4]) = ov;
        } else {
            const float4 mean = make_float4(tot.x * (1.f / 16.f), tot.y * (1.f / 16.f),
                                            tot.z * (1.f / 16.f), tot.w * (1.f / 16.f));
            *reinterpret_cast<float4*>(&cat[r][D + 4 * d4]) = mean;
        }
    }
    __syncthreads();

    // ---- layer 2: h[r][j] = relu(sum_k cat[r][k] * W2[j][k])
    // 2 j-outputs per thread, k split into 4 quarters of 64:
    // per k4-step: 4 uniform ds_read_b128 (broadcast) + 32 FMA  -> VALU-bound.
    {
        const int j0 = t & 63;             // j and j+64
        const int q  = t >> 6;             // k-quarter (wave-uniform)
        const float* w0 = W2 + (size_t)j0 * (2 * D) + q * 64;
        const float* w1 = W2 + (size_t)(j0 + 64) * (2 * D) + q * 64;
        float acc[SPB][2];
        #pragma unroll
        for (int r = 0; r < SPB; ++r) { acc[r][0] = 0.f; acc[r][1] = 0.f; }

        for (int k = 0; k < 64; k += 4) {
            const float4 a0 = *reinterpret_cast<const float4*>(w0 + k);
            const float4 a1 = *reinterpret_cast<const float4*>(w1 + k);
            #pragma unroll
            for (int r = 0; r < SPB; ++r) {
                const float4 c = *reinterpret_cast<const float4*>(&cat[r][q * 64 + k]);
                acc[r][0] = fmaf(a0.x, c.x, acc[r][0]);
                acc[r][0] = fmaf(a0.y, c.y, acc[r][0]);
                acc[r][0] = fmaf(a0.z, c.z, acc[r][0]);
                acc[r][0] = fmaf(a0.w, c.w, acc[r][0]);
                acc[r][1] = fmaf(a1.x, c.x, acc[r][1]);
                acc[r][1] = fmaf(a1.y, c.y, acc[r][1]);
                acc[r][1] = fmaf(a1.z, c.z, acc[r][1]);
                acc[r][1] = fmaf(a1.w, c.w, acc[r][1]);
            }
        }
        #pragma unroll
        for (int r = 0; r < SPB; ++r) {
            part[t][r * 2 + 0] = acc[r][0];
            part[t][r * 2 + 1] = acc[r][1];
        }
    }
    __syncthreads();

    // combine k-quarters + relu
    for (int i = t; i < SPB * H; i += THREADS) {   // 2 iterations
        const int r  = i >> 7;
        const int j  = i & (H - 1);
        const int jj = j >> 6;
        const int j0 = j & 63;
        float v = 0.f;
        #pragma unroll
        for (int q = 0; q < 4; ++q) v += part[(q << 6) | j0][r * 2 + jj];
        h[r][j] = v > 0.f ? v : 0.f;
    }
    __syncthreads();

    // ---- output layer + softmax: one wave per seed, lane = class (O=64)
    {
        const int lane = t & 63;
        const int r    = t >> 6;
        const float* wo = Wo + (size_t)lane * H;
        float acc = 0.f;
        #pragma unroll
        for (int k = 0; k < H; k += 4) {
            const float4 wv = *reinterpret_cast<const float4*>(wo + k);
            acc = fmaf(wv.x, h[r][k + 0], acc);
            acc = fmaf(wv.y, h[r][k + 1], acc);
            acc = fmaf(wv.z, h[r][k + 2], acc);
            acc = fmaf(wv.w, h[r][k + 3], acc);
        }
        float m = acc;
        #pragma unroll
        for (int off = 32; off >= 1; off >>= 1)
            m = fmaxf(m, __shfl_xor(m, off));
        const float e = __expf(acc - m);
        float ssum = e;
        #pragma unroll
        for (int off = 32; off >= 1; off >>= 1)
            ssum += __shfl_xor(ssum, off);
        out[(size_t)(seed0 + r) * O + lane] = e / ssum;
    }
}

extern "C" void kernel_launch(void* const* d_in, const int* in_sizes, int n_in,
                              void* d_out, int out_size, void* d_ws, size_t ws_size,
                              hipStream_t stream) {
    const int*   nodes         = (const int*)d_in[0];
    const int*   neighbors_1   = (const int*)d_in[1];
    const float* node_features = (const float*)d_in[3];
    const float* W2            = (const float*)d_in[5];
    const float* Wo            = (const float*)d_in[6];
    float*       out           = (float*)d_out;

    sage_fused<<<NB / SPB, THREADS, 0, stream>>>(
        nodes, neighbors_1, node_features, W2, Wo, out);
}

// Round 5
// 126.574 us; speedup vs baseline: 1.0931x; 1.0931x over previous
//
#include <hip/hip_runtime.h>

// GraphSAGE fused forward — live path only (neighbors_2/W1 are dead code).
// Round-3 profile showed latency/scatter-bound (VALUBusy 8%, HBM 4%, warm-cache
// replay still 52us): per-lane W2/Wo row loads touched 64 cache lines per
// instruction. Fix: two kernels; ALL weight reads go through LDS with T2-style
// XOR quad-swizzle (conflict-free b128), no scattered global loads anywhere.
//
//   d_in[0] nodes        int32 [4096]
//   d_in[1] neighbors_1  int32 [4096,16]
//   d_in[2] neighbors_2  (UNUSED)
//   d_in[3] node_features f32  [100000,128]
//   d_in[4] W1           (UNUSED)
//   d_in[5] W2           f32   [128,256]
//   d_in[6] Wo           f32   [64,128]
// out: softmax(relu(cat[feat, mean_nbr] @ W2^T) @ Wo^T)  f32 [4096,64]

constexpr int D = 128;
constexpr int H = 128;
constexpr int O = 64;
constexpr int S = 16;
constexpr int NB = 4096;

// ---------------- K1: gather + mean -> cat[NB][2D] in workspace --------------
// One 64-lane wave per seed; lanes split 2x32 (neighbor halves). Every load
// instruction moves 2 x 512B fully-coalesced row segments. 4096 waves of TLP.
__global__ __launch_bounds__(64) void k_gather(
    const int* __restrict__ nodes,
    const int* __restrict__ neigh,
    const float* __restrict__ nf,
    float* __restrict__ cat)
{
    const int seed = blockIdx.x;
    const int lane = threadIdx.x;          // 0..63
    const int d4   = lane & 31;            // float4 column
    const int sub  = lane >> 5;            // neighbor half
    const float4* nf4 = reinterpret_cast<const float4*>(nf);

    const int4* nbp = reinterpret_cast<const int4*>(neigh + (size_t)seed * S + sub * 8);
    const int4 n0 = nbp[0], n1 = nbp[1];
    const int ids[8] = {n0.x, n0.y, n0.z, n0.w, n1.x, n1.y, n1.z, n1.w};

    float4 sum = make_float4(0.f, 0.f, 0.f, 0.f);
    #pragma unroll
    for (int s = 0; s < 8; ++s) {          // 8 independent loads in flight
        const float4 v = nf4[(size_t)ids[s] * (D / 4) + d4];
        sum.x += v.x; sum.y += v.y; sum.z += v.z; sum.w += v.w;
    }
    float4 tot;
    tot.x = sum.x + __shfl_xor(sum.x, 32);
    tot.y = sum.y + __shfl_xor(sum.y, 32);
    tot.z = sum.z + __shfl_xor(sum.z, 32);
    tot.w = sum.w + __shfl_xor(sum.w, 32);

    float4* o4 = reinterpret_cast<float4*>(cat + (size_t)seed * (2 * D));
    if (sub == 0) {
        o4[d4] = nf4[(size_t)nodes[seed] * (D / 4) + d4];          // origin
    } else {
        o4[32 + d4] = make_float4(tot.x * 0.0625f, tot.y * 0.0625f,
                                  tot.z * 0.0625f, tot.w * 0.0625f); // mean
    }
}

// ---------------- K2: MLP (layer2 + relu + output + softmax) -----------------
constexpr int SPB = 8;    // seeds per block -> 512 blocks, 2 blocks/CU
constexpr int KP  = 32;   // W2 k-panel width

__global__ __launch_bounds__(256, 2) void k_mlp(
    const float* __restrict__ cat,
    const float* __restrict__ W2,
    const float* __restrict__ Wo,
    float* __restrict__ out)
{
    __shared__ float catl[SPB][2 * D];   //  8 KB
    __shared__ float w2l[2][H][KP];      // 32 KB, XOR quad-swizzled
    __shared__ float wol[O][D];          // 32 KB, XOR quad-swizzled
    __shared__ float hl[SPB][H];         //  4 KB            total 76 KB

    const int t  = threadIdx.x;
    const int s0 = blockIdx.x * SPB;

    // ---- issue all phase-0 global loads up front (latency overlapped) ----
    float4 pv[4];                         // W2 panel 0, coalesced 128B segments
    #pragma unroll
    for (int i = 0; i < 4; ++i) {
        const int idx = t + i * 256, row = idx >> 3, c4 = idx & 7;
        pv[i] = *reinterpret_cast<const float4*>(W2 + (size_t)row * (2 * D) + c4 * 4);
    }
    float4 cv0, cv1;                      // cat tile, fully coalesced
    {
        const float4* cg = reinterpret_cast<const float4*>(cat + (size_t)s0 * 2 * D);
        cv0 = cg[t]; cv1 = cg[t + 256];
    }
    float4 wv[8];                         // Wo (32 KB), fully coalesced
    #pragma unroll
    for (int i = 0; i < 8; ++i)
        wv[i] = reinterpret_cast<const float4*>(Wo)[t + i * 256];

    // ---- LDS writes (swizzled where scatter-read later) ----
    {
        float4* cl = reinterpret_cast<float4*>(&catl[0][0]);
        cl[t] = cv0; cl[t + 256] = cv1;
    }
    #pragma unroll
    for (int i = 0; i < 8; ++i) {         // wol[c][k4 ^ (c&7)]
        const int idx = t + i * 256, c = idx >> 5, k4 = idx & 31;
        *reinterpret_cast<float4*>(&wol[c][((k4 & 24) | ((k4 ^ c) & 7)) << 2]) = wv[i];
    }

    const int j0 = t & 63;                // W2 rows j0 and j0+64 (same swizzle)
    const int sg = t >> 6;                // seed group 0..3
    const int sA = sg * 2, sB = sA + 1;
    const int swz = j0 & 7;
    float acc00 = 0.f, acc01 = 0.f, acc10 = 0.f, acc11 = 0.f; // [jA/jB][sA/sB]

    // ---- 8 W2 panels, double-buffered; prefetch p+1 under compute(p) ----
    for (int p = 0; p < 8; ++p) {
        const int cur = p & 1;
        #pragma unroll
        for (int i = 0; i < 4; ++i) {     // w2l[row][c4 ^ (row&7)]
            const int idx = t + i * 256, row = idx >> 3, c4 = idx & 7;
            *reinterpret_cast<float4*>(&w2l[cur][row][(c4 ^ (row & 7)) << 2]) = pv[i];
        }
        __syncthreads();
        if (p < 7) {
            #pragma unroll
            for (int i = 0; i < 4; ++i) {
                const int idx = t + i * 256, row = idx >> 3, c4 = idx & 7;
                pv[i] = *reinterpret_cast<const float4*>(
                    W2 + (size_t)row * (2 * D) + (p + 1) * KP + c4 * 4);
            }
        }
        #pragma unroll
        for (int k4 = 0; k4 < 8; ++k4) {
            const float4 wA = *reinterpret_cast<const float4*>(&w2l[cur][j0][(k4 ^ swz) << 2]);
            const float4 wB = *reinterpret_cast<const float4*>(&w2l[cur][j0 + 64][(k4 ^ swz) << 2]);
            const float4 cA = *reinterpret_cast<const float4*>(&catl[sA][p * KP + k4 * 4]);
            const float4 cB = *reinterpret_cast<const float4*>(&catl[sB][p * KP + k4 * 4]);
            acc00 = fmaf(wA.x, cA.x, acc00); acc00 = fmaf(wA.y, cA.y, acc00);
            acc00 = fmaf(wA.z, cA.z, acc00); acc00 = fmaf(wA.w, cA.w, acc00);
            acc01 = fmaf(wA.x, cB.x, acc01); acc01 = fmaf(wA.y, cB.y, acc01);
            acc01 = fmaf(wA.z, cB.z, acc01); acc01 = fmaf(wA.w, cB.w, acc01);
            acc10 = fmaf(wB.x, cA.x, acc10); acc10 = fmaf(wB.y, cA.y, acc10);
            acc10 = fmaf(wB.z, cA.z, acc10); acc10 = fmaf(wB.w, cA.w, acc10);
            acc11 = fmaf(wB.x, cB.x, acc11); acc11 = fmaf(wB.y, cB.y, acc11);
            acc11 = fmaf(wB.z, cB.z, acc11); acc11 = fmaf(wB.w, cB.w, acc11);
        }
        __syncthreads();
    }

    // ---- relu -> hl ----
    hl[sA][j0]      = acc00 > 0.f ? acc00 : 0.f;
    hl[sB][j0]      = acc01 > 0.f ? acc01 : 0.f;
    hl[sA][j0 + 64] = acc10 > 0.f ? acc10 : 0.f;
    hl[sB][j0 + 64] = acc11 > 0.f ? acc11 : 0.f;
    __syncthreads();

    // ---- output layer + softmax: lane = class, wave sg handles seeds sA,sB ----
    {
        const int c = t & 63;
        const int cswz = c & 7;
        float a0 = 0.f, a1 = 0.f;
        #pragma unroll
        for (int k4 = 0; k4 < 32; ++k4) {
            const float4 w = *reinterpret_cast<const float4*>(
                &wol[c][((k4 & 24) | ((k4 ^ cswz) & 7)) << 2]);
            const float4 h0 = *reinterpret_cast<const float4*>(&hl[sA][k4 * 4]);
            const float4 h1 = *reinterpret_cast<const float4*>(&hl[sB][k4 * 4]);
            a0 = fmaf(w.x, h0.x, a0); a0 = fmaf(w.y, h0.y, a0);
            a0 = fmaf(w.z, h0.z, a0); a0 = fmaf(w.w, h0.w, a0);
            a1 = fmaf(w.x, h1.x, a1); a1 = fmaf(w.y, h1.y, a1);
            a1 = fmaf(w.z, h1.z, a1); a1 = fmaf(w.w, h1.w, a1);
        }
        float m0 = a0, m1 = a1;
        #pragma unroll
        for (int off = 32; off >= 1; off >>= 1) {
            m0 = fmaxf(m0, __shfl_xor(m0, off));
            m1 = fmaxf(m1, __shfl_xor(m1, off));
        }
        const float e0 = __expf(a0 - m0), e1 = __expf(a1 - m1);
        float z0 = e0, z1 = e1;
        #pragma unroll
        for (int off = 32; off >= 1; off >>= 1) {
            z0 += __shfl_xor(z0, off);
            z1 += __shfl_xor(z1, off);
        }
        out[(size_t)(s0 + sA) * O + c] = e0 / z0;
        out[(size_t)(s0 + sB) * O + c] = e1 / z1;
    }
}

extern "C" void kernel_launch(void* const* d_in, const int* in_sizes, int n_in,
                              void* d_out, int out_size, void* d_ws, size_t ws_size,
                              hipStream_t stream) {
    const int*   nodes         = (const int*)d_in[0];
    const int*   neighbors_1   = (const int*)d_in[1];
    const float* node_features = (const float*)d_in[3];
    const float* W2            = (const float*)d_in[5];
    const float* Wo            = (const float*)d_in[6];
    float*       out           = (float*)d_out;
    float*       cat           = (float*)d_ws;   // [4096][256] f32 = 4 MB

    k_gather<<<NB, 64, 0, stream>>>(nodes, neighbors_1, node_features, cat);
    k_mlp<<<NB / SPB, 256, 0, stream>>>(cat, W2, Wo, out);
}

// Round 6
// 122.624 us; speedup vs baseline: 1.1283x; 1.0322x over previous
//
#include <hip/hip_runtime.h>

// GraphSAGE fused forward — live path only (neighbors_2/W1 are dead code).
// Fused single kernel = r2 structure (512 blocks, SPB=8) + r5's LDS-staged
// XOR-swizzled weights (removes the r3 scatter: 64 cache lines per lane-row
// load instruction). Gather feeds LDS directly — no d_ws round-trip, 1 launch.
//
//   d_in[0] nodes        int32 [4096]
//   d_in[1] neighbors_1  int32 [4096,16]
//   d_in[2] neighbors_2  (UNUSED)
//   d_in[3] node_features f32  [100000,128]
//   d_in[4] W1           (UNUSED)
//   d_in[5] W2           f32   [128,256]
//   d_in[6] Wo           f32   [64,128]
// out: softmax(relu(cat[feat, mean_nbr] @ W2^T) @ Wo^T)  f32 [4096,64]

constexpr int D = 128;
constexpr int H = 128;
constexpr int O = 64;
constexpr int S = 16;
constexpr int NB = 4096;
constexpr int SPB = 8;     // 512 blocks, 2 blocks/CU (LDS-bound)
constexpr int KP  = 32;    // W2 k-panel width

__global__ __launch_bounds__(256, 2) void sage_fused(
    const int* __restrict__ nodes,
    const int* __restrict__ neigh,
    const float* __restrict__ nf,
    const float* __restrict__ W2,
    const float* __restrict__ Wo,
    float* __restrict__ out)
{
    __shared__ float catl[SPB][2 * D];   //  8 KB  [origin | mean]
    __shared__ float w2l[2][H][KP];      // 32 KB  XOR quad-swizzled, dbuf
    __shared__ float wol[O][D];          // 32 KB  XOR quad-swizzled
    __shared__ float hl[SPB][H];         //  4 KB             total 76 KB

    const int t  = threadIdx.x;
    const int s0 = blockIdx.x * SPB;

    // ---- issue W2 panel-0 loads first (coalesced 128B row segments) ----
    float4 pv[4];
    #pragma unroll
    for (int i = 0; i < 4; ++i) {
        const int idx = t + i * 256, row = idx >> 3, c4 = idx & 7;
        pv[i] = *reinterpret_cast<const float4*>(W2 + (size_t)row * (2 * D) + c4 * 4);
    }

    // ---- gather: wave w owns seeds 2w, 2w+1. Lanes split 2x32 neighbor
    // halves; 16 independent 1KB row loads + 2 origin loads in flight. ----
    {
        const int lane = t & 63;
        const int wv_  = t >> 6;
        const int d4   = lane & 31;
        const int sub  = lane >> 5;
        const float4* nf4 = reinterpret_cast<const float4*>(nf);

        int ids[2][8];
        #pragma unroll
        for (int si = 0; si < 2; ++si) {
            const int4* nbp = reinterpret_cast<const int4*>(
                neigh + (size_t)(s0 + 2 * wv_ + si) * S + sub * 8);
            const int4 a = nbp[0], b = nbp[1];
            ids[si][0] = a.x; ids[si][1] = a.y; ids[si][2] = a.z; ids[si][3] = a.w;
            ids[si][4] = b.x; ids[si][5] = b.y; ids[si][6] = b.z; ids[si][7] = b.w;
        }
        float4 sum[2] = {make_float4(0.f, 0.f, 0.f, 0.f),
                         make_float4(0.f, 0.f, 0.f, 0.f)};
        float4 orgv[2];
        #pragma unroll
        for (int si = 0; si < 2; ++si)
            orgv[si] = nf4[(size_t)nodes[s0 + 2 * wv_ + si] * (D / 4) + d4];
        #pragma unroll
        for (int k = 0; k < 8; ++k) {
            #pragma unroll
            for (int si = 0; si < 2; ++si) {
                const float4 v = nf4[(size_t)ids[si][k] * (D / 4) + d4];
                sum[si].x += v.x; sum[si].y += v.y;
                sum[si].z += v.z; sum[si].w += v.w;
            }
        }
        #pragma unroll
        for (int si = 0; si < 2; ++si) {
            float4 tot;
            tot.x = sum[si].x + __shfl_xor(sum[si].x, 32);
            tot.y = sum[si].y + __shfl_xor(sum[si].y, 32);
            tot.z = sum[si].z + __shfl_xor(sum[si].z, 32);
            tot.w = sum[si].w + __shfl_xor(sum[si].w, 32);
            const int s = 2 * wv_ + si;
            if (sub == 0) {
                *reinterpret_cast<float4*>(&catl[s][4 * d4]) = orgv[si];
            } else {
                *reinterpret_cast<float4*>(&catl[s][D + 4 * d4]) =
                    make_float4(tot.x * 0.0625f, tot.y * 0.0625f,
                                tot.z * 0.0625f, tot.w * 0.0625f);
            }
        }
    }

    // ---- Wo loads (coalesced), then swizzled LDS writes ----
    float4 wv[8];
    #pragma unroll
    for (int i = 0; i < 8; ++i)
        wv[i] = reinterpret_cast<const float4*>(Wo)[t + i * 256];
    #pragma unroll
    for (int i = 0; i < 8; ++i) {         // wol[c][k4 ^ (c&7)] quad-swizzle
        const int idx = t + i * 256, c = idx >> 5, k4 = idx & 31;
        *reinterpret_cast<float4*>(&wol[c][((k4 & 24) | ((k4 ^ c) & 7)) << 2]) = wv[i];
    }

    const int j0  = t & 63;               // W2 rows j0, j0+64
    const int sg  = t >> 6;               // seed group
    const int sA  = sg * 2, sB = sA + 1;
    const int swz = j0 & 7;
    float acc00 = 0.f, acc01 = 0.f, acc10 = 0.f, acc11 = 0.f;

    // ---- 8 W2 panels, double-buffered; prefetch p+1 under compute(p) ----
    for (int p = 0; p < 8; ++p) {
        const int cur = p & 1;
        #pragma unroll
        for (int i = 0; i < 4; ++i) {     // w2l[row][c4 ^ (row&7)]
            const int idx = t + i * 256, row = idx >> 3, c4 = idx & 7;
            *reinterpret_cast<float4*>(&w2l[cur][row][(c4 ^ (row & 7)) << 2]) = pv[i];
        }
        __syncthreads();
        if (p < 7) {
            #pragma unroll
            for (int i = 0; i < 4; ++i) {
                const int idx = t + i * 256, row = idx >> 3, c4 = idx & 7;
                pv[i] = *reinterpret_cast<const float4*>(
                    W2 + (size_t)row * (2 * D) + (p + 1) * KP + c4 * 4);
            }
        }
        #pragma unroll
        for (int k4 = 0; k4 < 8; ++k4) {
            const float4 wA = *reinterpret_cast<const float4*>(&w2l[cur][j0][(k4 ^ swz) << 2]);
            const float4 wB = *reinterpret_cast<const float4*>(&w2l[cur][j0 + 64][(k4 ^ swz) << 2]);
            const float4 cA = *reinterpret_cast<const float4*>(&catl[sA][p * KP + k4 * 4]);
            const float4 cB = *reinterpret_cast<const float4*>(&catl[sB][p * KP + k4 * 4]);
            acc00 = fmaf(wA.x, cA.x, acc00); acc00 = fmaf(wA.y, cA.y, acc00);
            acc00 = fmaf(wA.z, cA.z, acc00); acc00 = fmaf(wA.w, cA.w, acc00);
            acc01 = fmaf(wA.x, cB.x, acc01); acc01 = fmaf(wA.y, cB.y, acc01);
            acc01 = fmaf(wA.z, cB.z, acc01); acc01 = fmaf(wA.w, cB.w, acc01);
            acc10 = fmaf(wB.x, cA.x, acc10); acc10 = fmaf(wB.y, cA.y, acc10);
            acc10 = fmaf(wB.z, cA.z, acc10); acc10 = fmaf(wB.w, cA.w, acc10);
            acc11 = fmaf(wB.x, cB.x, acc11); acc11 = fmaf(wB.y, cB.y, acc11);
            acc11 = fmaf(wB.z, cB.z, acc11); acc11 = fmaf(wB.w, cB.w, acc11);
        }
        __syncthreads();
    }

    // ---- relu -> hl ----
    hl[sA][j0]      = acc00 > 0.f ? acc00 : 0.f;
    hl[sB][j0]      = acc01 > 0.f ? acc01 : 0.f;
    hl[sA][j0 + 64] = acc10 > 0.f ? acc10 : 0.f;
    hl[sB][j0 + 64] = acc11 > 0.f ? acc11 : 0.f;
    __syncthreads();

    // ---- output layer + softmax: lane = class; wave sg does seeds sA,sB ----
    {
        const int c = t & 63;
        const int cswz = c & 7;
        float a0 = 0.f, a1 = 0.f;
        #pragma unroll
        for (int k4 = 0; k4 < 32; ++k4) {
            const float4 w = *reinterpret_cast<const float4*>(
                &wol[c][((k4 & 24) | ((k4 ^ cswz) & 7)) << 2]);
            const float4 h0 = *reinterpret_cast<const float4*>(&hl[sA][k4 * 4]);
            const float4 h1 = *reinterpret_cast<const float4*>(&hl[sB][k4 * 4]);
            a0 = fmaf(w.x, h0.x, a0); a0 = fmaf(w.y, h0.y, a0);
            a0 = fmaf(w.z, h0.z, a0); a0 = fmaf(w.w, h0.w, a0);
            a1 = fmaf(w.x, h1.x, a1); a1 = fmaf(w.y, h1.y, a1);
            a1 = fmaf(w.z, h1.z, a1); a1 = fmaf(w.w, h1.w, a1);
        }
        float m0 = a0, m1 = a1;
        #pragma unroll
        for (int off = 32; off >= 1; off >>= 1) {
            m0 = fmaxf(m0, __shfl_xor(m0, off));
            m1 = fmaxf(m1, __shfl_xor(m1, off));
        }
        const float e0 = __expf(a0 - m0), e1 = __expf(a1 - m1);
        float z0 = e0, z1 = e1;
        #pragma unroll
        for (int off = 32; off >= 1; off >>= 1) {
            z0 += __shfl_xor(z0, off);
            z1 += __shfl_xor(z1, off);
        }
        out[(size_t)(s0 + sA) * O + c] = e0 / z0;
        out[(size_t)(s0 + sB) * O + c] = e1 / z1;
    }
}

extern "C" void kernel_launch(void* const* d_in, const int* in_sizes, int n_in,
                              void* d_out, int out_size, void* d_ws, size_t ws_size,
                              hipStream_t stream) {
    const int*   nodes         = (const int*)d_in[0];
    const int*   neighbors_1   = (const int*)d_in[1];
    const float* node_features = (const float*)d_in[3];
    const float* W2            = (const float*)d_in[5];
    const float* Wo            = (const float*)d_in[6];
    float*       out           = (float*)d_out;

    sage_fused<<<NB / SPB, 256, 0, stream>>>(
        nodes, neighbors_1, node_features, W2, Wo, out);
}